// Round 9
// baseline (574.616 us; speedup 1.0000x reference)
//
#include <hip/hip_runtime.h>
#include <math.h>

#define BATCH 128
#define S 50
#define D 128
#define SAMPLE 12

typedef __attribute__((ext_vector_type(8))) short short8v;
typedef __attribute__((ext_vector_type(4))) float f32x4;
typedef unsigned short u16;

__device__ __forceinline__ float leakyf(float x) { return x >= 0.f ? x : 0.2f * x; }
__device__ __forceinline__ u16 f2bf(float f) {
    union { float f; unsigned u; } v; v.f = f;
    unsigned u = v.u;
    return (u16)((u + 0x7FFFu + ((u >> 16) & 1u)) >> 16);  // RNE
}
__device__ __forceinline__ float bf2f(u16 h) {
    union { float f; unsigned u; } v; v.u = ((unsigned)h) << 16; return v.f;
}

// ---------------------------------------------------------------------------
// setup1: session + n1 (1-hop indices) + nw0 (1-hop weights)
// ---------------------------------------------------------------------------
__global__ __launch_bounds__(256) void setup1_kernel(
    const int* __restrict__ item, const int* __restrict__ mask,
    const int* __restrict__ inputs, const int* __restrict__ adj_all,
    const float* __restrict__ num_weight, const float* __restrict__ emb,
    float* __restrict__ session, int* __restrict__ n1, float* __restrict__ nw0)
{
    const int bx = blockIdx.x, t = threadIdx.x;
    if (bx < BATCH) {
        if (t < 128) {
            float num = 0.f, den = 0.f;
            for (int s = 0; s < S; ++s) {
                float m = (float)mask[bx * S + s];
                num += m * emb[item[bx * S + s] * D + t];
                den += m;
            }
            session[bx * D + t] = num / den;
        }
    } else {
        int idx = (bx - BATCH) * 256 + t;
        if (idx < BATCH * 600) {
            int b = idx / 600, j = idx % 600;
            int node = inputs[b * S + j / SAMPLE];
            n1[idx]  = adj_all[node * SAMPLE + j % SAMPLE];
            nw0[idx] = num_weight[node * SAMPLE + j % SAMPLE];
        }
    }
}

// ---------------------------------------------------------------------------
// prep2: emb->bf16, sessW1 bf16, W3T bf16, n2o (2-hop BYTE offsets, plain
// order) + nw1 (2-hop weights, plain order)
// ---------------------------------------------------------------------------
__global__ __launch_bounds__(256) void prep2_kernel(
    const float* __restrict__ emb, const float* __restrict__ w1,
    const float* __restrict__ w3, const float* __restrict__ session,
    const int* __restrict__ adj_all, const float* __restrict__ num_weight,
    const int* __restrict__ n1,
    u16* __restrict__ emb_bf, u16* __restrict__ sw1, u16* __restrict__ w3t,
    int* __restrict__ n2o, float* __restrict__ nw1)
{
    const int bx = blockIdx.x, t = threadIdx.x;
    if (bx < 2500) {                       // embedding -> bf16, 8 elems/thread
        int idx = bx * 256 + t;
        const float4* src = reinterpret_cast<const float4*>(emb) + (size_t)idx * 2;
        float4 a = src[0], c = src[1];
        u16 o[8] = {f2bf(a.x), f2bf(a.y), f2bf(a.z), f2bf(a.w),
                    f2bf(c.x), f2bf(c.y), f2bf(c.z), f2bf(c.w)};
        *reinterpret_cast<uint4*>(emb_bf + (size_t)idx * 8) = *reinterpret_cast<uint4*>(o);
    } else if (bx < 2756) {                // sessW1: block = (hop,b)
        int id = bx - 2500, hop = id >> 7, b = id & 127;
        const float* w1s = w1 + hop * 129 * 128;
        const float* se = session + b * 128;
        int n = t >> 1, kh = (t & 1) * 64;
        u16* dst = sw1 + (((size_t)(hop * 128 + b) * 128 + n) * 128) + kh;
        for (int kq = 0; kq < 64; kq += 8) {
            u16 o[8];
            #pragma unroll
            for (int e = 0; e < 8; ++e) { int k = kh + kq + e; o[e] = f2bf(w1s[k * 128 + n] * se[k]); }
            *reinterpret_cast<uint4*>(dst + kq) = *reinterpret_cast<uint4*>(o);
        }
    } else if (bx < 2788) {                // W3T [hop][n][k]
        int j = (bx - 2756) * 256 + t;     // < 8192
        int hop = j >> 12, r = j & 4095, n = r >> 5, k0 = (r & 31) * 8;
        const float* w3s = w3 + hop * 256 * 128;
        u16 o[8];
        #pragma unroll
        for (int e = 0; e < 8; ++e) o[e] = f2bf(w3s[(k0 + e) * 128 + n]);
        *reinterpret_cast<uint4*>(w3t + ((size_t)hop * 128 + n) * 256 + k0) = *reinterpret_cast<uint4*>(o);
    } else {                               // n2o byte-offsets + nw1 (plain)
        int idx = (bx - 2788) * 256 + t;
        if (idx < BATCH * 7200) {
            int b = idx / 7200, j = idx % 7200;
            int node = n1[b * 600 + j / SAMPLE];
            int s = j % SAMPLE;
            n2o[idx] = adj_all[node * SAMPLE + s] << 8;
            nw1[idx] = num_weight[node * SAMPLE + s];
        }
    }
}

// ---------------------------------------------------------------------------
// Fused main kernel. 512 threads = 8 waves; ONE l (12 samples) per wave; one
// block = 8 l-rows. Per wave: gather A-rows DIRECTLY into MFMA fragments (no
// staging barrier), GEMM1 (M=16 pad / N=128 / K=128), wave-local score +
// softmax via shfl, phase-4 from a wave-private swizzled LDS copy (same-wave,
// lgkmcnt only), write one A2 row. ONE block barrier, then GEMM2 (wave = 16
// output cols). Waves progress independently -> continuous gather stream
// instead of the block-wide burst that stalled r2-r8 at ~60%.
//
// PATH 0, grid (83,128): bx==0 -> local_agg; bx 1..7 -> mode0; bx 8..82 -> mode1.
// PATH 2, grid (7,128):  mode2 (self=out0, neigh=out1, hop1) += d_out.
//
// Register discipline (r5/r6 lesson): no per-lane f32 array may live across an
// MFMA loop. Here: acc[8] (32) + aF[4] (16) + scalars; unified < 128 at
// __launch_bounds__(512,4).
// ---------------------------------------------------------------------------
template <int PATH>
__global__ __launch_bounds__(512, 4) void main_kernel(
    const int* __restrict__ inputs, const int* __restrict__ adj,
    const u16* __restrict__ emb_bf, const float* __restrict__ a_local,
    const int* __restrict__ n1, const int* __restrict__ n2o,
    const float* __restrict__ nw0, const float* __restrict__ nw1,
    const u16* __restrict__ sw1, const float* __restrict__ w1,
    const float* __restrict__ w2, const u16* __restrict__ w3t,
    const u16* __restrict__ in0, const u16* __restrict__ in1,
    u16* __restrict__ o0, u16* __restrict__ o1, float* __restrict__ outf)
{
    __shared__ __align__(16) char smem[41472];
    const int b = blockIdx.y;
    const int t = threadIdx.x;
    const int bx = blockIdx.x;

    if (PATH == 0 && bx == 0) {
        // ------------------- local aggregation (512-thread version) -------
        u16*   ht    = (u16*)smem;              // [128][52] bf16 = 13312 B
        float* alpha = (float*)(smem + 13312);  // [50][51] f32  = 10200 B
        u16*   alb   = (u16*)(smem + 23520);    // [4][128] bf16 = 1024 B

        for (int idx = t; idx < S * D; idx += 512) {
            int i = idx >> 7, d = idx & 127;
            ht[d * 52 + i] = emb_bf[(size_t)inputs[b * S + i] * D + d];
        }
        if (t < 512) { if (t < 512 && t < 512) {} }
        for (int idx = t; idx < 512; idx += 512) alb[idx] = f2bf(a_local[idx]);
        __syncthreads();

        for (int p = t; p < S * S; p += 512) {
            int i = p / S, j = p % S;
            int a = adj[b * S * S + p];
            float v = -9e15f;
            if (a >= 1 && a <= 4) {
                const u16* ak = alb + (a - 1) * D;
                float dot = 0.f;
                #pragma unroll 4
                for (int d = 0; d < D; ++d)
                    dot += bf2f(ht[d * 52 + i]) * bf2f(ht[d * 52 + j]) * bf2f(ak[d]);
                v = leakyf(dot);
            }
            alpha[i * 51 + j] = v;
        }
        __syncthreads();

        if (t < S) {
            float m = -INFINITY;
            for (int j = 0; j < S; ++j) m = fmaxf(m, alpha[t * 51 + j]);
            float ssum = 0.f;
            for (int j = 0; j < S; ++j) { float e = __expf(alpha[t * 51 + j] - m); alpha[t * 51 + j] = e; ssum += e; }
            float inv = 1.f / ssum;
            for (int j = 0; j < S; ++j) alpha[t * 51 + j] *= inv;
        }
        __syncthreads();

        for (int idx = t; idx < S * D; idx += 512) {
            int i = idx >> 7, d = idx & 127;
            float acc = 0.f;
            #pragma unroll 5
            for (int j = 0; j < S; ++j) acc += alpha[i * 51 + j] * bf2f(ht[d * 52 + j]);
            outf[(size_t)b * S * D + idx] = acc;
        }
        return;
    }

    // ------------------- global aggregation -------------------
    int mode, lblk, L, hop, nstr;
    const u16 *nsrc, *ssrc;
    const float* nwTab;
    u16* outb;
    if (PATH == 2)    { mode = 2; lblk = bx;     L = 50;  hop = 1; nstr = 600;  nsrc = in1;    ssrc = in0;    nwTab = nw0; outb = nullptr; }
    else if (bx >= 8) { mode = 1; lblk = bx - 8; L = 600; hop = 0; nstr = 7200; nsrc = emb_bf; ssrc = emb_bf; nwTab = nw1; outb = o1; }
    else              { mode = 0; lblk = bx - 1; L = 50;  hop = 0; nstr = 600;  nsrc = emb_bf; ssrc = emb_bf; nwTab = nw0; outb = o0; }
    const int l0 = lblk * 8;

    const int wv = t >> 6, lane = t & 63, cn = lane & 15, cg = lane >> 4;
    const int l = l0 + wv;
    const int lc = (l < L) ? l : (L - 1);      // clamped for gathers/OOB safety

    u16*   nvw   = (u16*)(smem) + wv * 2048;   // wave-private 16x128 bf16 (4KB)
    u16*   A2    = (u16*)(smem + 32768);       // 512 frag-slots * 16B = 8KB
    float* alphL = (float*)(smem + 40960);     // 8 waves * 16 = 512B

    const u16*   sw1b   = sw1 + (size_t)(hop * 128 + b) * 16384;
    const float* w1last = w1 + hop * 129 * 128 + 128 * 128;
    const float* w2h    = w2 + hop * 128;
    const u16*   w3th   = w3t + hop * 32768;

    // ---- gather my sample row straight into A fragments (no barrier) ----
    int sidx = (cn < 12) ? cn : 11;
    unsigned off;
    if (mode == 1)      off = (unsigned)n2o[b * 7200 + lc * 12 + sidx];
    else if (mode == 0) off = (unsigned)n1[b * 600 + lc * 12 + sidx] << 8;
    else                off = (unsigned)(b * 600 + lc * 12 + sidx) << 8;

    short8v aF[4];
    #pragma unroll
    for (int kk = 0; kk < 4; ++kk)
        aF[kk] = *reinterpret_cast<const short8v*>((const char*)nsrc + off + (kk * 32 + cg * 8) * 2);
    // wave-private LDS copy for phase-4 (XOR-swizzled, conflict-free)
    #pragma unroll
    for (int kk = 0; kk < 4; ++kk)
        *reinterpret_cast<short8v*>((char*)nvw + cn * 256 + ((kk * 64 + cg * 16) ^ ((cn & 7) << 4))) = aF[kk];

    // per-lane neigh-weights for my 4 C-rows
    float nwr[4];
    #pragma unroll
    for (int r = 0; r < 4; ++r) {
        int row = cg * 4 + r; int rr = (row < 12) ? row : 11;
        nwr[r] = nwTab[b * nstr + lc * 12 + rr];
    }

    // ---- self row (lanes 0..15 of each wave) + A2 pad-row zeroing ----
    if (lane < 16) {
        int kk = lane >> 2, cg2 = lane & 3;
        int lg = l; if (lg >= L) lg = 0;
        int srow;
        if (PATH == 2)      srow = b * 50 + lg;
        else if (mode == 1) srow = n1[b * 600 + lg];
        else                srow = inputs[b * S + lg];
        uint4 v = *reinterpret_cast<const uint4*>(ssrc + (size_t)srow * 128 + kk * 32 + cg2 * 8);
        *reinterpret_cast<uint4*>(A2 + (kk * 64 + cg2 * 16 + wv) * 8) = v;
    } else if (lane < 48) {
        int idx = wv * 32 + (lane - 16);       // 0..255: kk(8) x cg(4) x row8..15
        int slot = (idx >> 5) * 64 + ((idx >> 3) & 3) * 16 + 8 + (idx & 7);
        *reinterpret_cast<uint4*>(A2 + slot * 8) = make_uint4(0, 0, 0, 0);
    }

    // ---- GEMM1: z[16(12),128] = A @ sessW1, A from registers ----
    f32x4 acc[8];
    #pragma unroll
    for (int nt = 0; nt < 8; ++nt) acc[nt] = (f32x4){0.f, 0.f, 0.f, 0.f};
    #pragma unroll
    for (int kk = 0; kk < 4; ++kk) {
        #pragma unroll
        for (int nt = 0; nt < 8; ++nt) {
            short8v bF = *reinterpret_cast<const short8v*>(sw1b + (nt * 16 + cn) * 128 + kk * 32 + cg * 8);
            acc[nt] = __builtin_amdgcn_mfma_f32_16x16x32_bf16(aF[kk], bF, acc[nt], 0, 0, 0);
        }
    }

    // ---- score: K=129 rank-1 + leaky + @W2, reduce over cols (shfl on cn) ----
    float sc[4];
    #pragma unroll
    for (int r = 0; r < 4; ++r) {
        float v = 0.f;
        #pragma unroll
        for (int nt = 0; nt < 8; ++nt) {
            int ncol = nt * 16 + cn;
            v += leakyf(acc[nt][r] + nwr[r] * w1last[ncol]) * w2h[ncol];
        }
        v += __shfl_xor(v, 1); v += __shfl_xor(v, 2);
        v += __shfl_xor(v, 4); v += __shfl_xor(v, 8);
        sc[r] = v;                       // score[row=cg*4+r], uniform over cn
    }
    // ---- wave-local softmax over rows 0..11 (shfl on cg) ----
    {
        float mx = -1e30f;
        #pragma unroll
        for (int r = 0; r < 4; ++r) if (cg * 4 + r < 12) mx = fmaxf(mx, sc[r]);
        mx = fmaxf(mx, __shfl_xor(mx, 16)); mx = fmaxf(mx, __shfl_xor(mx, 32));
        float e[4]; float sm = 0.f;
        #pragma unroll
        for (int r = 0; r < 4; ++r) {
            e[r] = (cg * 4 + r < 12) ? __expf(sc[r] - mx) : 0.f;
            sm += e[r];
        }
        sm += __shfl_xor(sm, 16); sm += __shfl_xor(sm, 32);
        float inv = 1.f / sm;
        if (cn == 0) {
            #pragma unroll
            for (int r = 0; r < 4; ++r)
                if (cg * 4 + r < 12) alphL[wv * 16 + cg * 4 + r] = e[r] * inv;
        }
    }

    // ---- phase 4 (same-wave, no barrier): neigh[d] = sum_s alpha*nv ----
    {
        float a0 = 0.f, a1 = 0.f;          // d = lane*2, lane*2+1
        #pragma unroll
        for (int s2 = 0; s2 < 12; ++s2) {
            unsigned pk = *reinterpret_cast<const unsigned*>(
                (const char*)nvw + s2 * 256 + ((lane * 4) ^ ((s2 & 7) << 4)));
            float al = alphL[wv * 16 + s2];
            a0 += al * bf2f((u16)(pk & 0xffff));
            a1 += al * bf2f((u16)(pk >> 16));
        }
        unsigned pk2 = ((unsigned)f2bf(a1) << 16) | f2bf(a0);
        int slot = (4 + cg) * 64 + ((lane >> 2) & 3) * 16 + wv;
        *reinterpret_cast<unsigned*>((char*)A2 + slot * 16 + (lane & 3) * 4) = pk2;
    }
    __syncthreads();                       // the ONLY block barrier

    // ---- GEMM2: out[16,128] = A2 @ W3T; wave = 16 output cols ----
    {
        f32x4 acc2 = (f32x4){0.f, 0.f, 0.f, 0.f};
        int nc = wv * 16 + cn;
        #pragma unroll
        for (int kk2 = 0; kk2 < 8; ++kk2) {
            short8v a2 = *reinterpret_cast<const short8v*>(A2 + (kk2 * 64 + lane) * 8);
            short8v bb = *reinterpret_cast<const short8v*>(w3th + nc * 256 + kk2 * 32 + cg * 8);
            acc2 = __builtin_amdgcn_mfma_f32_16x16x32_bf16(a2, bb, acc2, 0, 0, 0);
        }
        if (cg < 2) {                      // C rows 0..7 = l-rows, 8..15 pad
            #pragma unroll
            for (int r = 0; r < 4; ++r) {
                int row = cg * 4 + r;
                int lg = l0 + row;
                float v = fmaxf(acc2[r], 0.f);
                if (lg < L) {
                    if (PATH == 2) { float* p = outf + ((size_t)b * 50 + lg) * 128 + nc; *p += v; }
                    else           outb[((size_t)b * L + lg) * 128 + nc] = f2bf(v);
                }
            }
        }
    }
}

// ---------------------------------------------------------------------------
extern "C" void kernel_launch(void* const* d_in, const int* in_sizes, int n_in,
                              void* d_out, int out_size, void* d_ws, size_t ws_size,
                              hipStream_t stream)
{
    const int*   inputs     = (const int*)d_in[0];
    const int*   adj        = (const int*)d_in[1];
    const int*   mask_item  = (const int*)d_in[2];
    const int*   item       = (const int*)d_in[3];
    const int*   adj_all    = (const int*)d_in[4];
    const float* num_weight = (const float*)d_in[5];
    const float* embedding  = (const float*)d_in[6];
    const float* a_local    = (const float*)d_in[7];
    const float* agg_w1     = (const float*)d_in[8];
    const float* agg_w2     = (const float*)d_in[9];
    const float* agg_w3     = (const float*)d_in[10];
    float* out = (float*)d_out;

    // workspace layout (16B aligned)
    char* w = (char*)d_ws;
    float* ws_session = (float*)(w);               //     65,536 B
    int*   ws_n1      = (int*)(w + 65536);         //    307,200 B
    float* ws_nw0     = (float*)(w + 372736);      //    307,200 B
    float* ws_nw1     = (float*)(w + 679936);      //  3,686,400 B
    int*   ws_n2o     = (int*)(w + 4366336);       //  3,686,400 B
    u16*   ws_emb     = (u16*)(w + 8052736);       // 10,240,000 B
    u16*   ws_sw1     = (u16*)(w + 18292736);      //  8,388,608 B
    u16*   ws_w3t     = (u16*)(w + 26681344);      //    131,072 B
    u16*   ws_out0    = (u16*)(w + 26812416);      //  1,638,400 B
    u16*   ws_out1    = (u16*)(w + 28450816);      // 19,660,800 B (end ~45.9 MB)

    setup1_kernel<<<dim3(BATCH + 300), 256, 0, stream>>>(
        item, mask_item, inputs, adj_all, num_weight, embedding,
        ws_session, ws_n1, ws_nw0);
    prep2_kernel<<<dim3(6388), 256, 0, stream>>>(
        embedding, agg_w1, agg_w3, ws_session, adj_all, num_weight, ws_n1,
        ws_emb, ws_sw1, ws_w3t, ws_n2o, ws_nw1);

    // fused: local (bx=0) + mode0 (bx 1..7) + mode1 (bx 8..82) per batch
    main_kernel<0><<<dim3(83, BATCH), 512, 0, stream>>>(
        inputs, adj, ws_emb, a_local, ws_n1, ws_n2o, ws_nw0, ws_nw1,
        ws_sw1, agg_w1, agg_w2, ws_w3t,
        nullptr, nullptr, ws_out0, ws_out1, out);

    // mode2: hop-1 weights, self=out0, neigh=out1, += h_local in d_out
    main_kernel<2><<<dim3(7, BATCH), 512, 0, stream>>>(
        inputs, adj, ws_emb, a_local, ws_n1, ws_n2o, ws_nw0, ws_nw1,
        ws_sw1, agg_w1, agg_w2, ws_w3t,
        ws_out0, ws_out1, nullptr, nullptr, out);
}

// Round 10
// 403.088 us; speedup vs baseline: 1.4255x; 1.4255x over previous
//
#include <hip/hip_runtime.h>
#include <math.h>

#define BATCH 128
#define S 50
#define D 128
#define SAMPLE 12

typedef __attribute__((ext_vector_type(8))) short short8v;
typedef __attribute__((ext_vector_type(4))) float f32x4;
typedef unsigned short u16;

__device__ __forceinline__ float leakyf(float x) { return x >= 0.f ? x : 0.2f * x; }
__device__ __forceinline__ u16 f2bf(float f) {
    union { float f; unsigned u; } v; v.f = f;
    unsigned u = v.u;
    return (u16)((u + 0x7FFFu + ((u >> 16) & 1u)) >> 16);  // RNE
}
__device__ __forceinline__ float bf2f(u16 h) {
    union { float f; unsigned u; } v; v.u = ((unsigned)h) << 16; return v.f;
}
__device__ __forceinline__ void gld_lds16(const void* g, void* l) {
    __builtin_amdgcn_global_load_lds(
        (const __attribute__((address_space(1))) void*)g,
        (__attribute__((address_space(3))) void*)l, 16, 0, 0);
}
// LDS-only barrier: does NOT drain vmcnt, so prefetch gathers stay in flight.
__device__ __forceinline__ void barrier_lds_only() {
    asm volatile("s_waitcnt lgkmcnt(0)" ::: "memory");
    __builtin_amdgcn_s_barrier();
}

// ---------------------------------------------------------------------------
// setup1: session + n1 (1-hop indices) + nw0 (1-hop weights)
// ---------------------------------------------------------------------------
__global__ __launch_bounds__(256) void setup1_kernel(
    const int* __restrict__ item, const int* __restrict__ mask,
    const int* __restrict__ inputs, const int* __restrict__ adj_all,
    const float* __restrict__ num_weight, const float* __restrict__ emb,
    float* __restrict__ session, int* __restrict__ n1, float* __restrict__ nw0)
{
    const int bx = blockIdx.x, t = threadIdx.x;
    if (bx < BATCH) {
        if (t < 128) {
            float num = 0.f, den = 0.f;
            for (int s = 0; s < S; ++s) {
                float m = (float)mask[bx * S + s];
                num += m * emb[item[bx * S + s] * D + t];
                den += m;
            }
            session[bx * D + t] = num / den;
        }
    } else {
        int idx = (bx - BATCH) * 256 + t;
        if (idx < BATCH * 600) {
            int b = idx / 600, j = idx % 600;
            int node = inputs[b * S + j / SAMPLE];
            n1[idx]  = adj_all[node * SAMPLE + j % SAMPLE];
            nw0[idx] = num_weight[node * SAMPLE + j % SAMPLE];
        }
    }
}

// ---------------------------------------------------------------------------
// prep2: emb->bf16, sessW1 bf16, W3T bf16, permuted gather tables (byte offs),
// nw1 (plain order), and sfo (self-row byte offsets per unified task).
// ---------------------------------------------------------------------------
__global__ __launch_bounds__(256) void prep2_kernel(
    const float* __restrict__ emb, const float* __restrict__ w1,
    const float* __restrict__ w3, const float* __restrict__ session,
    const int* __restrict__ adj_all, const float* __restrict__ num_weight,
    const int* __restrict__ n1, const int* __restrict__ inputs,
    u16* __restrict__ emb_bf, u16* __restrict__ sw1, u16* __restrict__ w3t,
    int* __restrict__ n2p, int* __restrict__ n1p, float* __restrict__ nw1,
    int* __restrict__ sfo)
{
    const int bx = blockIdx.x, t = threadIdx.x;
    if (bx < 2500) {                       // embedding -> bf16
        int idx = bx * 256 + t;
        const float4* src = reinterpret_cast<const float4*>(emb) + (size_t)idx * 2;
        float4 a = src[0], c = src[1];
        u16 o[8] = {f2bf(a.x), f2bf(a.y), f2bf(a.z), f2bf(a.w),
                    f2bf(c.x), f2bf(c.y), f2bf(c.z), f2bf(c.w)};
        *reinterpret_cast<uint4*>(emb_bf + (size_t)idx * 8) = *reinterpret_cast<uint4*>(o);
    } else if (bx < 2756) {                // sessW1: block = (hop,b)
        int id = bx - 2500, hop = id >> 7, b = id & 127;
        const float* w1s = w1 + hop * 129 * 128;
        const float* se = session + b * 128;
        int n = t >> 1, kh = (t & 1) * 64;
        u16* dst = sw1 + (((size_t)(hop * 128 + b) * 128 + n) * 128) + kh;
        for (int kq = 0; kq < 64; kq += 8) {
            u16 o[8];
            #pragma unroll
            for (int e = 0; e < 8; ++e) { int k = kh + kq + e; o[e] = f2bf(w1s[k * 128 + n] * se[k]); }
            *reinterpret_cast<uint4*>(dst + kq) = *reinterpret_cast<uint4*>(o);
        }
    } else if (bx < 2788) {                // W3T [hop][n][k]
        int j = (bx - 2756) * 256 + t;
        int hop = j >> 12, r = j & 4095, n = r >> 5, k0 = (r & 31) * 8;
        const float* w3s = w3 + hop * 256 * 128;
        u16 o[8];
        #pragma unroll
        for (int e = 0; e < 8; ++e) o[e] = f2bf(w3s[(k0 + e) * 128 + n]);
        *reinterpret_cast<uint4*>(w3t + ((size_t)hop * 128 + n) * 256 + k0) = *reinterpret_cast<uint4*>(o);
    } else if (bx < 6388) {                // n2p (permuted byte-offsets) + nw1
        int idx = (bx - 2788) * 256 + t;
        if (idx < BATCH * 7200) {
            int b = idx / 7200, r = idx % 7200;
            int lblk = r / 96, q = r % 96;
            int i = q >> 4, c = q & 15;
            int gm = lblk * 96 + (c >> 2) * 24 + i * 4 + (c & 3);
            int node = n1[b * 600 + gm / SAMPLE];
            int s = gm % SAMPLE;
            n2p[idx] = adj_all[node * SAMPLE + s] << 8;
            nw1[b * 7200 + gm] = num_weight[node * SAMPLE + s];
        }
    } else if (bx < 6724) {                // n1p (mode0, permuted byte-offsets)
        int idx = (bx - 6388) * 256 + t;
        if (idx < BATCH * 672) {
            int b = idx / 672, r = idx % 672;
            int lblk = r / 96, q = r % 96;
            int i = q >> 4, c = q & 15;
            int gm = lblk * 96 + (c >> 2) * 24 + i * 4 + (c & 3);
            int jc = (gm < 600) ? gm : 0;
            n1p[idx] = n1[b * 600 + jc] << 8;
        }
    } else {                               // sfo: self-row byte offsets per task
        int idx = (bx - 6724) * 256 + t;
        if (idx < BATCH * 82 * 16) {
            int b = idx / (82 * 16), r2 = idx % (82 * 16), u = r2 >> 4, r = r2 & 15;
            int sov;
            if (u < 75) {
                int l = u * 8 + (r & 7);
                sov = n1[b * 600 + l] << 8;
            } else {
                int l = (u - 75) * 8 + (r & 7); if (l >= 50) l = 0;
                sov = inputs[b * S + l] << 8;
            }
            sfo[idx] = sov;
        }
    }
}

template <int PATH>
__device__ __forceinline__ void ldregs(int u, int b, int t, int cidx, int task0,
    const int* __restrict__ n2p, const int* __restrict__ n1p,
    const float* __restrict__ nw0, const float* __restrict__ nw1,
    unsigned po[6], float& nwr)
{
    if (PATH == 0) {
        const int* pt; const float* nws;
        if (u < 75) { pt = n2p + (b * 75 + u) * 96; nws = nw1 + (size_t)b * 7200 + (size_t)u * 96; }
        else        { pt = n1p + (b * 7 + (u - 75)) * 96; nws = nw0 + (size_t)b * 600 + (size_t)(u - 75) * 96; }
        #pragma unroll
        for (int i = 0; i < 6; ++i) po[i] = (unsigned)pt[i * 16 + cidx];
        nwr = (t < 96) ? nws[t] : 0.f;
    } else {
        int l0_ = task0 * 8;
        #pragma unroll
        for (int i = 0; i < 6; ++i) {
            int gm = l0_ * 12 + (cidx >> 2) * 24 + i * 4 + (cidx & 3);
            if (gm > 599) gm = 599;
            po[i] = (unsigned)((b * 600 + gm) << 8);
        }
        int mm = l0_ * 12 + t; if (mm > 599) mm = 599;
        nwr = (t < 96) ? nw0[(size_t)b * 600 + mm] : 0.f;
    }
}

template <int PATH>
__device__ __forceinline__ unsigned ldsoff(int u, int b, int cS, int task0,
                                           const int* __restrict__ sfo)
{
    if (PATH == 0) return (unsigned)sfo[(b * 82 + u) * 16 + cS];
    int lg = task0 * 8 + (cS & 7); if (lg >= 50) lg = 0;
    return (unsigned)((b * 50 + lg) << 8);
}

// ---------------------------------------------------------------------------
// Persistent pipelined kernel. 256 threads, 2 blocks/CU (60KB LDS).
// PATH 0: grid (4,128). Block (s,b) runs tasks st[s]..st[s+1]-1 of the 82
//   unified tasks (0-74 mode1 -> out1; 75-81 mode0 -> out0); s==0 also runs
//   local_agg at the end. Software pipeline: global_load_lds gathers for
//   task i+1 issued at top of iter i; intra-iter barriers are raw s_barrier
//   + lgkmcnt(0) only (no vmcnt drain); end-of-iter __syncthreads drains.
// PATH 2: grid (7,128), one task per block (mode2: self=out0, neigh=out1,
//   hop-1 weights, += d_out which holds h_local).
// Register discipline: sessW1 B-fragments hoisted to regs (32 VGPR) so the
// GEMM1 loop has NO vmem; no per-lane f32 array crosses an MFMA loop.
// ---------------------------------------------------------------------------
template <int PATH>
__global__ __launch_bounds__(256, 2) void persist_kernel(
    const int* __restrict__ inputs, const int* __restrict__ adj,
    const u16* __restrict__ emb_bf, const float* __restrict__ a_local,
    const int* __restrict__ n2p, const int* __restrict__ n1p,
    const int* __restrict__ sfo,
    const float* __restrict__ nw0, const float* __restrict__ nw1,
    const u16* __restrict__ sw1, const float* __restrict__ w1,
    const float* __restrict__ w2, const u16* __restrict__ w3t,
    const u16* __restrict__ in0, const u16* __restrict__ in1,
    u16* __restrict__ o0, u16* __restrict__ o1, float* __restrict__ outf)
{
    __shared__ __align__(16) char smem[60032];
    const int b = blockIdx.y;
    const int s = blockIdx.x;
    const int t = threadIdx.x;

    int task0, ntask;
    if (PATH == 0) {
        const int st0[5] = {0, 20, 41, 62, 82};
        task0 = st0[s]; ntask = st0[s + 1] - task0;
    } else { task0 = s; ntask = 1; }
    const int taskL = task0 + ntask - 1;

    u16* nvLb0     = (u16*)smem;               // 24576 B
    u16* nvLb1     = (u16*)(smem + 24576);     // 24576 B
    u16* A2        = (u16*)(smem + 49152);     //  8192 B
    float* score_w = (float*)(smem + 57344);   //  1536 B
    float* nwgt    = (float*)(smem + 58880);   //   768 B ([2][96])
    float* alphL   = (float*)(smem + 59648);   //   384 B

    const int hop = (PATH == 2) ? 1 : 0;
    const u16*   sw1b   = sw1 + (size_t)(hop * 128 + b) * 16384;
    const float* w1last = w1 + hop * 129 * 128 + 128 * 128;
    const float* w2h    = w2 + hop * 128;
    const u16*   w3th   = w3t + hop * 32768;
    const u16*   nsrc   = (PATH == 2) ? in1 : emb_bf;
    const u16*   ssrc   = (PATH == 2) ? in0 : emb_bf;

    const int lane = t & 63, wv = t >> 6, cn = lane & 15, cg = lane >> 4;
    const int nc0 = (2 * wv) * 16 + cn, nc1 = (2 * wv + 1) * 16 + cn;
    const int cS = t & 15, chunk = t >> 4;
    const int cidx = cS ^ ((((t >> 6) & 1) << 2) | ((t >> 4) & 3));  // swz perm

    // ---- hoist GEMM1 B fragments + epilogue scalars (loop-invariant) ----
    short8v B1a[4], B1b[4];
    #pragma unroll
    for (int kk = 0; kk < 4; ++kk) {
        B1a[kk] = *reinterpret_cast<const short8v*>(sw1b + nc0 * 128 + kk * 32 + cg * 8);
        B1b[kk] = *reinterpret_cast<const short8v*>(sw1b + nc1 * 128 + kk * 32 + cg * 8);
    }
    const float w2v0 = w2h[nc0], w2v1 = w2h[nc1];
    const float w1l0 = w1last[nc0], w1l1 = w1last[nc1];

    // ---- prologue: prefetch + stage task0 ----
    unsigned po[6]; float nwr; unsigned soff; uint4 sdat;
    ldregs<PATH>(task0, b, t, cidx, task0, n2p, n1p, nw0, nw1, po, nwr);
    soff = ldsoff<PATH>(task0, b, cS, task0, sfo);
    {
        char* db = (char*)nvLb0 + wv * 1024;
        #pragma unroll
        for (int i = 0; i < 6; ++i)
            gld_lds16((const char*)nsrc + po[i] + chunk * 16, db + i * 4096);
    }
    if (t < 96) nwgt[t] = nwr;
    sdat = *reinterpret_cast<const uint4*>((const char*)ssrc + soff + chunk * 16);
    {
        int un = (task0 + 1 < taskL) ? task0 + 1 : taskL;
        ldregs<PATH>(un, b, t, cidx, task0, n2p, n1p, nw0, nw1, po, nwr);
        soff = ldsoff<PATH>(un, b, cS, task0, sfo);
    }
    __syncthreads();                           // drains: nvL buf0 ready

    for (int i = 0; i < ntask; ++i) {
        const int cur = i & 1;
        u16* nvL = cur ? nvLb1 : nvLb0;

        // top: self rows of current task -> A2 lower half (slot = t)
        *reinterpret_cast<uint4*>(A2 + t * 8) = sdat;

        // stage next task (gathers async into other buffer) + nw
        if (i + 1 < ntask) {
            char* db = (char*)(cur ? nvLb0 : nvLb1) + wv * 1024;
            #pragma unroll
            for (int q = 0; q < 6; ++q)
                gld_lds16((const char*)nsrc + po[q] + chunk * 16, db + q * 4096);
            if (t < 96) nwgt[(cur ^ 1) * 96 + t] = nwr;
        }
        // advance prefetch regs (sdat for i+1; tables for i+2)
        sdat = *reinterpret_cast<const uint4*>((const char*)ssrc + soff + chunk * 16);
        {
            int u2 = (task0 + i + 2 < taskL) ? task0 + i + 2 : taskL;
            ldregs<PATH>(u2, b, t, cidx, task0, n2p, n1p, nw0, nw1, po, nwr);
            soff = ldsoff<PATH>(u2, b, cS, task0, sfo);
        }

        // ---- GEMM1: z[96,128] = nv @ sessW1 (B from regs, zero vmem) ----
        f32x4 acc[6][2];
        #pragma unroll
        for (int mt = 0; mt < 6; ++mt) {
            acc[mt][0] = (f32x4){0.f, 0.f, 0.f, 0.f};
            acc[mt][1] = (f32x4){0.f, 0.f, 0.f, 0.f};
        }
        #pragma unroll
        for (int kk = 0; kk < 4; ++kk) {
            int lslot = cg * 16 + (cn ^ (((kk & 1) << 2) | cg));
            #pragma unroll
            for (int mt = 0; mt < 6; ++mt) {
                short8v a = *reinterpret_cast<const short8v*>(nvL + ((mt * 4 + kk) * 64 + lslot) * 8);
                acc[mt][0] = __builtin_amdgcn_mfma_f32_16x16x32_bf16(a, B1a[kk], acc[mt][0], 0, 0, 0);
                acc[mt][1] = __builtin_amdgcn_mfma_f32_16x16x32_bf16(a, B1b[kk], acc[mt][1], 0, 0, 0);
            }
        }
        // ---- score: K=129 rank-1 + leaky + @W2, reduce over 16 lanes ----
        {
            const float* nwg = nwgt + cur * 96;
            #pragma unroll
            for (int mt = 0; mt < 6; ++mt) {
                #pragma unroll
                for (int r = 0; r < 4; ++r) {
                    int m = cg * 24 + mt * 4 + r;
                    float nw = nwg[m];
                    float v = leakyf(acc[mt][0][r] + nw * w1l0) * w2v0 +
                              leakyf(acc[mt][1][r] + nw * w1l1) * w2v1;
                    v += __shfl_xor(v, 1); v += __shfl_xor(v, 2);
                    v += __shfl_xor(v, 4); v += __shfl_xor(v, 8);
                    if (cn == 0) score_w[m * 4 + wv] = v;
                }
            }
        }
        barrier_lds_only();                    // LDS-only: gathers stay in flight

        // ---- per-lane redundant softmax for l=2cg,2cg+1 -> alphL ----
        {
            float alph[24];
            const f32x4* sw4 = reinterpret_cast<const f32x4*>(score_w);
            float mx0 = -1e30f, mx1 = -1e30f;
            #pragma unroll
            for (int q = 0; q < 24; ++q) {
                f32x4 s4 = sw4[cg * 24 + q];
                float sv = (s4[0] + s4[1]) + (s4[2] + s4[3]);
                alph[q] = sv;
                if (q < 12) mx0 = fmaxf(mx0, sv); else mx1 = fmaxf(mx1, sv);
            }
            float sm0 = 0.f, sm1 = 0.f;
            #pragma unroll
            for (int q = 0; q < 12; ++q)  { alph[q] = __expf(alph[q] - mx0); sm0 += alph[q]; }
            #pragma unroll
            for (int q = 12; q < 24; ++q) { alph[q] = __expf(alph[q] - mx1); sm1 += alph[q]; }
            float i0 = 1.f / sm0, i1 = 1.f / sm1;
            if (cn == 0) {
                #pragma unroll
                for (int q = 0; q < 12; ++q)  alphL[(cg * 2) * 12 + q] = alph[q] * i0;
                #pragma unroll
                for (int q = 12; q < 24; ++q) alphL[(cg * 2 + 1) * 12 + (q - 12)] = alph[q] * i1;
            }
        }
        // ---- phase 4: neigh[l][d] = sum_s alpha*nv -> A2 upper half ----
        #pragma unroll 1
        for (int ii = 0; ii < 4; ++ii) {
            int idx = ii * 256 + t;
            int l = idx >> 7, d = idx & 127;
            int kkd = d >> 5, cgd = (d >> 3) & 3, el = d & 7;
            int cnb = (l >> 1) * 4, mtb = (l & 1) * 3;
            int fd = ((kkd & 1) << 2) | cgd;
            float a = 0.f;
            #pragma unroll
            for (int s2 = 0; s2 < 12; ++s2) {
                int slot = ((mtb + (s2 >> 2)) * 4 + kkd) * 64 + cgd * 16 + ((cnb + (s2 & 3)) ^ fd);
                a += alphL[l * 12 + s2] * bf2f(nvL[slot * 8 + el]);
            }
            A2[((4 + kkd) * 64 + cgd * 16 + l) * 8 + el] = f2bf(a);
        }
        barrier_lds_only();                    // A2 visible; gathers untouched

        // ---- GEMM2: out[16,128] = A2[16,256] @ W3T ----
        {
            int uu = task0 + i;
            u16* outp = nullptr; int l0c, Lc;
            if (PATH == 0) {
                if (uu < 75) { outp = o1; l0c = uu * 8; Lc = 600; }
                else         { outp = o0; l0c = (uu - 75) * 8; Lc = 50; }
            } else { l0c = task0 * 8; Lc = 50; }

            #pragma unroll
            for (int j = 0; j < 2; ++j) {
                int nc = (2 * wv + j) * 16 + cn;
                f32x4 acc2 = (f32x4){0.f, 0.f, 0.f, 0.f};
                #pragma unroll
                for (int kk2 = 0; kk2 < 8; ++kk2) {
                    short8v a2 = *reinterpret_cast<const short8v*>(A2 + (kk2 * 64 + lane) * 8);
                    short8v bb = *reinterpret_cast<const short8v*>(w3th + nc * 256 + kk2 * 32 + cg * 8);
                    acc2 = __builtin_amdgcn_mfma_f32_16x16x32_bf16(a2, bb, acc2, 0, 0, 0);
                }
                if (cg < 2) {                  // C rows 0..7 valid; 8..15 pad
                    #pragma unroll
                    for (int r = 0; r < 4; ++r) {
                        int lg = l0c + cg * 4 + r;
                        float v = fmaxf(acc2[r], 0.f);
                        if (lg < Lc) {
                            if (PATH == 2) { float* p = outf + ((size_t)b * 50 + lg) * 128 + nc; *p += v; }
                            else           outp[((size_t)b * Lc + lg) * 128 + nc] = f2bf(v);
                        }
                    }
                }
            }
        }
        __syncthreads();                       // full drain: next nvL buf ready
    }

    // ---- local aggregation appended to split 0 (PATH 0 only) ----
    if (PATH == 0 && s == 0) {
        u16*   ht    = (u16*)smem;              // [128][52] bf16 = 13312 B
        float* alpha = (float*)(smem + 13312);  // [50][51] f32  = 10200 B
        u16*   alb   = (u16*)(smem + 23520);    // [4][128] bf16 = 1024 B

        for (int idx = t; idx < S * D; idx += 256) {
            int i = idx >> 7, d = idx & 127;
            ht[d * 52 + i] = emb_bf[(size_t)inputs[b * S + i] * D + d];
        }
        for (int idx = t; idx < 512; idx += 256) alb[idx] = f2bf(a_local[idx]);
        __syncthreads();

        for (int p = t; p < S * S; p += 256) {
            int i = p / S, j = p % S;
            int a = adj[b * S * S + p];
            float v = -9e15f;
            if (a >= 1 && a <= 4) {
                const u16* ak = alb + (a - 1) * D;
                float dot = 0.f;
                #pragma unroll 4
                for (int d = 0; d < D; ++d)
                    dot += bf2f(ht[d * 52 + i]) * bf2f(ht[d * 52 + j]) * bf2f(ak[d]);
                v = leakyf(dot);
            }
            alpha[i * 51 + j] = v;
        }
        __syncthreads();

        if (t < S) {
            float m = -INFINITY;
            for (int j = 0; j < S; ++j) m = fmaxf(m, alpha[t * 51 + j]);
            float ssum = 0.f;
            for (int j = 0; j < S; ++j) { float e = __expf(alpha[t * 51 + j] - m); alpha[t * 51 + j] = e; ssum += e; }
            float inv = 1.f / ssum;
            for (int j = 0; j < S; ++j) alpha[t * 51 + j] *= inv;
        }
        __syncthreads();

        for (int idx = t; idx < S * D; idx += 256) {
            int i = idx >> 7, d = idx & 127;
            float acc = 0.f;
            #pragma unroll 5
            for (int j = 0; j < S; ++j) acc += alpha[i * 51 + j] * bf2f(ht[d * 52 + j]);
            outf[(size_t)b * S * D + idx] = acc;
        }
    }
}

// ---------------------------------------------------------------------------
extern "C" void kernel_launch(void* const* d_in, const int* in_sizes, int n_in,
                              void* d_out, int out_size, void* d_ws, size_t ws_size,
                              hipStream_t stream)
{
    const int*   inputs     = (const int*)d_in[0];
    const int*   adj        = (const int*)d_in[1];
    const int*   mask_item  = (const int*)d_in[2];
    const int*   item       = (const int*)d_in[3];
    const int*   adj_all    = (const int*)d_in[4];
    const float* num_weight = (const float*)d_in[5];
    const float* embedding  = (const float*)d_in[6];
    const float* a_local    = (const float*)d_in[7];
    const float* agg_w1     = (const float*)d_in[8];
    const float* agg_w2     = (const float*)d_in[9];
    const float* agg_w3     = (const float*)d_in[10];
    float* out = (float*)d_out;

    // workspace layout (16B aligned)
    char* w = (char*)d_ws;
    float* ws_session = (float*)(w);               //     65,536 B
    int*   ws_n1      = (int*)(w + 65536);         //    307,200 B
    float* ws_nw0     = (float*)(w + 372736);      //    307,200 B
    float* ws_nw1     = (float*)(w + 679936);      //  3,686,400 B
    int*   ws_n2p     = (int*)(w + 4366336);       //  3,686,400 B
    int*   ws_n1p     = (int*)(w + 8052736);       //    344,064 B
    int*   ws_sfo     = (int*)(w + 8396800);       //    671,744 B
    u16*   ws_emb     = (u16*)(w + 9068544);       // 10,240,000 B
    u16*   ws_sw1     = (u16*)(w + 19308544);      //  8,388,608 B
    u16*   ws_w3t     = (u16*)(w + 27697152);      //    131,072 B
    u16*   ws_out0    = (u16*)(w + 27828224);      //  1,638,400 B
    u16*   ws_out1    = (u16*)(w + 29466624);      // 19,660,800 B (end ~46.9 MB)

    setup1_kernel<<<dim3(BATCH + 300), 256, 0, stream>>>(
        item, mask_item, inputs, adj_all, num_weight, embedding,
        ws_session, ws_n1, ws_nw0);
    prep2_kernel<<<dim3(7380), 256, 0, stream>>>(
        embedding, agg_w1, agg_w3, ws_session, adj_all, num_weight, ws_n1,
        inputs, ws_emb, ws_sw1, ws_w3t, ws_n2p, ws_n1p, ws_nw1, ws_sfo);

    // persistent: 4 splits x 128 b; split 0 also does local_agg
    persist_kernel<0><<<dim3(4, BATCH), 256, 0, stream>>>(
        inputs, adj, ws_emb, a_local, ws_n2p, ws_n1p, ws_sfo, ws_nw0, ws_nw1,
        ws_sw1, agg_w1, agg_w2, ws_w3t,
        nullptr, nullptr, ws_out0, ws_out1, out);

    // mode2: one task per block; self=out0, neigh=out1, hop-1, += d_out
    persist_kernel<2><<<dim3(7, BATCH), 256, 0, stream>>>(
        inputs, adj, ws_emb, a_local, ws_n2p, ws_n1p, ws_sfo, ws_nw0, ws_nw1,
        ws_sw1, agg_w1, agg_w2, ws_w3t,
        ws_out0, ws_out1, nullptr, nullptr, out);
}

// Round 11
// 369.150 us; speedup vs baseline: 1.5566x; 1.0919x over previous
//
#include <hip/hip_runtime.h>
#include <math.h>

#define BATCH 128
#define S 50
#define D 128
#define SAMPLE 12

typedef __attribute__((ext_vector_type(8))) short short8v;
typedef __attribute__((ext_vector_type(4))) float f32x4;
typedef unsigned short u16;

__device__ __forceinline__ float leakyf(float x) { return x >= 0.f ? x : 0.2f * x; }
__device__ __forceinline__ u16 f2bf(float f) {
    union { float f; unsigned u; } v; v.f = f;
    unsigned u = v.u;
    return (u16)((u + 0x7FFFu + ((u >> 16) & 1u)) >> 16);  // RNE
}
__device__ __forceinline__ float bf2f(u16 h) {
    union { float f; unsigned u; } v; v.u = ((unsigned)h) << 16; return v.f;
}
__device__ __forceinline__ int swz(int cg, int kk) { return ((kk & 1) << 2) | cg; }

// ---------------------------------------------------------------------------
// setup1: session + n1 (1-hop indices) + nw0 (1-hop weights)
// ---------------------------------------------------------------------------
__global__ __launch_bounds__(256) void setup1_kernel(
    const int* __restrict__ item, const int* __restrict__ mask,
    const int* __restrict__ inputs, const int* __restrict__ adj_all,
    const float* __restrict__ num_weight, const float* __restrict__ emb,
    float* __restrict__ session, int* __restrict__ n1, float* __restrict__ nw0)
{
    const int bx = blockIdx.x, t = threadIdx.x;
    if (bx < BATCH) {
        if (t < 128) {
            float num = 0.f, den = 0.f;
            for (int s = 0; s < S; ++s) {
                float m = (float)mask[bx * S + s];
                num += m * emb[item[bx * S + s] * D + t];
                den += m;
            }
            session[bx * D + t] = num / den;
        }
    } else {
        int idx = (bx - BATCH) * 256 + t;
        if (idx < BATCH * 600) {
            int b = idx / 600, j = idx % 600;
            int node = inputs[b * S + j / SAMPLE];
            n1[idx]  = adj_all[node * SAMPLE + j % SAMPLE];
            nw0[idx] = num_weight[node * SAMPLE + j % SAMPLE];
        }
    }
}

// ---------------------------------------------------------------------------
// prep2: emb->bf16, sessW1 bf16, W3T bf16, permuted gather tables, nw1
// ---------------------------------------------------------------------------
__global__ __launch_bounds__(256) void prep2_kernel(
    const float* __restrict__ emb, const float* __restrict__ w1,
    const float* __restrict__ w3, const float* __restrict__ session,
    const int* __restrict__ adj_all, const float* __restrict__ num_weight,
    const int* __restrict__ n1,
    u16* __restrict__ emb_bf, u16* __restrict__ sw1, u16* __restrict__ w3t,
    int* __restrict__ n2p, int* __restrict__ n1p, float* __restrict__ nw1)
{
    const int bx = blockIdx.x, t = threadIdx.x;
    if (bx < 2500) {                       // embedding -> bf16
        int idx = bx * 256 + t;
        const float4* src = reinterpret_cast<const float4*>(emb) + (size_t)idx * 2;
        float4 a = src[0], c = src[1];
        u16 o[8] = {f2bf(a.x), f2bf(a.y), f2bf(a.z), f2bf(a.w),
                    f2bf(c.x), f2bf(c.y), f2bf(c.z), f2bf(c.w)};
        *reinterpret_cast<uint4*>(emb_bf + (size_t)idx * 8) = *reinterpret_cast<uint4*>(o);
    } else if (bx < 2756) {                // sessW1: block = (hop,b)
        int id = bx - 2500, hop = id >> 7, b = id & 127;
        const float* w1s = w1 + hop * 129 * 128;
        const float* se = session + b * 128;
        int n = t >> 1, kh = (t & 1) * 64;
        u16* dst = sw1 + (((size_t)(hop * 128 + b) * 128 + n) * 128) + kh;
        for (int kq = 0; kq < 64; kq += 8) {
            u16 o[8];
            #pragma unroll
            for (int e = 0; e < 8; ++e) { int k = kh + kq + e; o[e] = f2bf(w1s[k * 128 + n] * se[k]); }
            *reinterpret_cast<uint4*>(dst + kq) = *reinterpret_cast<uint4*>(o);
        }
    } else if (bx < 2788) {                // W3T [hop][n][k]
        int j = (bx - 2756) * 256 + t;
        int hop = j >> 12, r = j & 4095, n = r >> 5, k0 = (r & 31) * 8;
        const float* w3s = w3 + hop * 256 * 128;
        u16 o[8];
        #pragma unroll
        for (int e = 0; e < 8; ++e) o[e] = f2bf(w3s[(k0 + e) * 128 + n]);
        *reinterpret_cast<uint4*>(w3t + ((size_t)hop * 128 + n) * 256 + k0) = *reinterpret_cast<uint4*>(o);
    } else if (bx < 6388) {                // n2p (permuted byte-offsets) + nw1
        int idx = (bx - 2788) * 256 + t;
        if (idx < BATCH * 7200) {
            int b = idx / 7200, r = idx % 7200;
            int lblk = r / 96, q = r % 96;
            int i = q >> 4, c = q & 15;
            int gm = lblk * 96 + (c >> 2) * 24 + i * 4 + (c & 3);
            int node = n1[b * 600 + gm / SAMPLE];
            int s = gm % SAMPLE;
            n2p[idx] = adj_all[node * SAMPLE + s] << 8;
            nw1[b * 7200 + gm] = num_weight[node * SAMPLE + s];
        }
    } else {                               // n1p (mode0, permuted byte-offsets)
        int idx = (bx - 6388) * 256 + t;
        if (idx < BATCH * 672) {
            int b = idx / 672, r = idx % 672;
            int lblk = r / 96, q = r % 96;
            int i = q >> 4, c = q & 15;
            int gm = lblk * 96 + (c >> 2) * 24 + i * 4 + (c & 3);
            int jc = (gm < 600) ? gm : 0;
            n1p[idx] = n1[b * 600 + jc] << 8;
        }
    }
}

// ---------------------------------------------------------------------------
// Fused main kernel — OCCUPANCY build. 512 threads = 8 waves; wave w owns
// n-cols [w*16, w*16+16) of GEMM1/GEMM2 (acc = 24 AGPR, not 48) and l-row w
// for softmax/phase-4 (fully wave-local, no cross-wave alpha traffic).
// Target: <=85 unified VGPR -> 6 waves/SIMD (24 waves/CU) at 36.7KB LDS
// (3 blocks/CU). 2 barriers/tile. r5/r6 lesson: no per-lane f32 array may
// live across an MFMA loop.
//
// PATH 0, grid (83,128): bx==0 local_agg; bx 1..7 mode0 -> out0;
//                        bx 8..82 mode1 -> out1.
// PATH 2, grid (7,128):  mode2 (self=out0, neigh=out1, hop1) += d_out.
// ---------------------------------------------------------------------------
template <int PATH>
__global__ __launch_bounds__(512, 6) void main_kernel(
    const int* __restrict__ inputs, const int* __restrict__ adj,
    const u16* __restrict__ emb_bf, const float* __restrict__ a_local,
    const int* __restrict__ n1, const int* __restrict__ n2p,
    const int* __restrict__ n1p,
    const float* __restrict__ nw0, const float* __restrict__ nw1,
    const u16* __restrict__ sw1, const float* __restrict__ w1,
    const float* __restrict__ w2, const u16* __restrict__ w3t,
    const u16* __restrict__ in0, const u16* __restrict__ in1,
    u16* __restrict__ o0, u16* __restrict__ o1, float* __restrict__ outf)
{
    __shared__ __align__(16) char smem[36736];
    const int b = blockIdx.y;
    const int t = threadIdx.x;
    const int bx = blockIdx.x;

    if (PATH == 0 && bx == 0) {
        // ------------------- local aggregation -------------------
        u16*   ht    = (u16*)smem;              // [128][52] bf16
        float* alpha = (float*)(smem + 13312);  // [50][51] f32
        u16*   alb   = (u16*)(smem + 23520);    // [4][128] bf16

        for (int idx = t; idx < S * D; idx += 512) {
            int i = idx >> 7, d = idx & 127;
            ht[d * 52 + i] = emb_bf[(size_t)inputs[b * S + i] * D + d];
        }
        if (t < 512) alb[t] = f2bf(a_local[t]);
        __syncthreads();

        for (int p = t; p < S * S; p += 512) {
            int i = p / S, j = p % S;
            int a = adj[b * S * S + p];
            float v = -9e15f;
            if (a >= 1 && a <= 4) {
                const u16* ak = alb + (a - 1) * D;
                float dot = 0.f;
                #pragma unroll 4
                for (int d = 0; d < D; ++d)
                    dot += bf2f(ht[d * 52 + i]) * bf2f(ht[d * 52 + j]) * bf2f(ak[d]);
                v = leakyf(dot);
            }
            alpha[i * 51 + j] = v;
        }
        __syncthreads();

        if (t < S) {
            float m = -INFINITY;
            for (int j = 0; j < S; ++j) m = fmaxf(m, alpha[t * 51 + j]);
            float ssum = 0.f;
            for (int j = 0; j < S; ++j) { float e = __expf(alpha[t * 51 + j] - m); alpha[t * 51 + j] = e; ssum += e; }
            float inv = 1.f / ssum;
            for (int j = 0; j < S; ++j) alpha[t * 51 + j] *= inv;
        }
        __syncthreads();

        for (int idx = t; idx < S * D; idx += 512) {
            int i = idx >> 7, d = idx & 127;
            float acc = 0.f;
            #pragma unroll 5
            for (int j = 0; j < S; ++j) acc += alpha[i * 51 + j] * bf2f(ht[d * 52 + j]);
            outf[(size_t)b * S * D + idx] = acc;
        }
        return;
    }

    // ------------------- global aggregation -------------------
    int mode, lblk, L, Lm, hop;
    const u16 *nsrc, *ssrc;
    const int* ptab; const float* nwTab;
    u16* outb;
    if (PATH == 2)    { mode = 2; lblk = bx;     L = 50;  Lm = 600;  hop = 1; nsrc = in1;    ssrc = in0;    ptab = nullptr;                    nwTab = nw0; outb = nullptr; }
    else if (bx >= 8) { mode = 1; lblk = bx - 8; L = 600; Lm = 7200; hop = 0; nsrc = emb_bf; ssrc = emb_bf; ptab = n2p + (b * 75 + lblk) * 96; nwTab = nw1; outb = o1; }
    else              { mode = 0; lblk = bx - 1; L = 50;  Lm = 600;  hop = 0; nsrc = emb_bf; ssrc = emb_bf; ptab = n1p + (b * 7 + lblk) * 96;  nwTab = nw0; outb = o0; }
    const int l0 = lblk * 8;

    u16*   nvL     = (u16*)smem;              // 1536 frag-slots * 16B = 24576
    u16*   A2      = (u16*)(smem + 24576);    // 512 frag-slots * 16B = 8192
    float* score_w = (float*)(smem + 32768);  // [96][8] = 3072
    float* nwgtL   = (float*)(smem + 35840);  // 96 f32
    float* alphw   = (float*)(smem + 36224);  // [8][16] f32

    const u16*   sw1b   = sw1 + (size_t)(hop * 128 + b) * 16384;
    const float* w1last = w1 + hop * 129 * 128 + 128 * 128;
    const float* w2h    = w2 + hop * 128;
    const u16*   w3th   = w3t + hop * 32768;

    const int lane = t & 63, wv = t >> 6, cn = lane & 15, cg = lane >> 4;
    const int nc = wv * 16 + cn;              // this wave's output column

    // ---- stage 96 neighbor rows in fragment order (3 x uint4 / thread) ----
    #pragma unroll
    for (int i = 0; i < 3; ++i) {
        int slot = i * 512 + t;               // [mt(6)][kk(4)][cg(4)][c(16)]
        int mt = slot >> 8, kkS = (slot >> 6) & 3;
        int cgS = (slot >> 4) & 3, cS = slot & 15;
        int cn2 = cS ^ swz(cgS, kkS);
        unsigned off;
        if (PATH == 2) {
            int gm = l0 * 12 + (cn2 >> 2) * 24 + mt * 4 + (cn2 & 3);
            if (gm > 599) gm = 599;
            off = (unsigned)((b * 600 + gm) << 8);
        } else {
            off = (unsigned)ptab[mt * 16 + cn2];
        }
        uint4 v = *reinterpret_cast<const uint4*>((const char*)nsrc + off + (kkS * 4 + cgS) * 16);
        *reinterpret_cast<uint4*>(nvL + slot * 8) = v;
    }
    // ---- self rows -> A2 low half; pad rows zero ----
    if (t < 256) {
        int chunk = t >> 4, cS = t & 15;
        uint4 v = make_uint4(0, 0, 0, 0);
        if (cS < 8) {
            int lg = l0 + cS; if (lg >= L) lg = 0;
            int srow;
            if (PATH == 2)      srow = b * 50 + lg;
            else if (mode == 1) srow = n1[b * 600 + lg];
            else                srow = inputs[b * S + lg];
            v = *reinterpret_cast<const uint4*>(ssrc + (size_t)srow * 128 + chunk * 8);
        }
        *reinterpret_cast<uint4*>(A2 + t * 8) = v;
    } else if (t < 384) {
        int t2 = t & 127;                     // zero A2 upper pad rows 8..15
        int slot = (4 + (t2 >> 5)) * 64 + ((t2 >> 3) & 3) * 16 + 8 + (t2 & 7);
        *reinterpret_cast<uint4*>(A2 + slot * 8) = make_uint4(0, 0, 0, 0);
    } else if (t < 480) {
        int m = t - 384;                      // 96 neigh-weights
        int gm = l0 * 12 + m;
        nwgtL[m] = (gm < Lm) ? nwTab[b * Lm + gm] : 0.f;
    }
    __syncthreads();

    // ---- GEMM1: z[96, nc] — wave owns 16 cols; acc = 24 AGPR ----
    f32x4 acc[6];
    #pragma unroll
    for (int mt = 0; mt < 6; ++mt) acc[mt] = (f32x4){0.f, 0.f, 0.f, 0.f};
    #pragma unroll
    for (int kk = 0; kk < 4; ++kk) {
        short8v bF = *reinterpret_cast<const short8v*>(sw1b + nc * 128 + kk * 32 + cg * 8);
        int lslot = cg * 16 + (cn ^ swz(cg, kk));
        #pragma unroll
        for (int mt = 0; mt < 6; ++mt) {
            short8v a = *reinterpret_cast<const short8v*>(nvL + ((mt * 4 + kk) * 64 + lslot) * 8);
            acc[mt] = __builtin_amdgcn_mfma_f32_16x16x32_bf16(a, bF, acc[mt], 0, 0, 0);
        }
    }
    // ---- score: K=129 rank-1 + leaky + @W2, reduce over 16 cols ----
    {
        float w2v = w2h[nc], w1lv = w1last[nc];
        #pragma unroll
        for (int mt = 0; mt < 6; ++mt) {
            #pragma unroll
            for (int r = 0; r < 4; ++r) {
                int m = cg * 24 + mt * 4 + r;
                float v = leakyf(acc[mt][r] + nwgtL[m] * w1lv) * w2v;
                v += __shfl_xor(v, 1); v += __shfl_xor(v, 2);
                v += __shfl_xor(v, 4); v += __shfl_xor(v, 8);
                if (cn == 0) score_w[m * 8 + wv] = v;
            }
        }
    }
    __syncthreads();

    // ---- wave-local softmax for l = wv (lane s = cn) ----
    {
        float sval = -1e30f;
        if (cn < 12) {
            int m = wv * 12 + cn;
            f32x4 p0 = *reinterpret_cast<const f32x4*>(score_w + m * 8);
            f32x4 p1 = *reinterpret_cast<const f32x4*>(score_w + m * 8 + 4);
            sval = ((p0[0] + p0[1]) + (p0[2] + p0[3])) +
                   ((p1[0] + p1[1]) + (p1[2] + p1[3]));
        }
        float mx = sval;
        mx = fmaxf(mx, __shfl_xor(mx, 1)); mx = fmaxf(mx, __shfl_xor(mx, 2));
        mx = fmaxf(mx, __shfl_xor(mx, 4)); mx = fmaxf(mx, __shfl_xor(mx, 8));
        float e = (cn < 12) ? __expf(sval - mx) : 0.f;
        float sm = e;
        sm += __shfl_xor(sm, 1); sm += __shfl_xor(sm, 2);
        sm += __shfl_xor(sm, 4); sm += __shfl_xor(sm, 8);
        if (cn < 12 && cg == 0) alphw[wv * 16 + cn] = e / sm;
    }

    // ---- phase 4 (same-wave): neigh[l=wv][d] -> A2 upper half ----
    {
        const int q = wv >> 1;                // row->slot inverse map
        const int remB = (wv & 1) * 12;
        const int d2 = lane;                  // d-pair index 0..63
        const int kk = d2 >> 4, cg2 = (d2 >> 2) & 3;
        const int fd = swz(cg2, kk);
        float a0 = 0.f, a1 = 0.f;
        #pragma unroll
        for (int s2 = 0; s2 < 12; ++s2) {
            int rem = remB + s2;
            int slot = ((rem >> 2) * 4 + kk) * 64 + cg2 * 16 + (((q << 2) | (rem & 3)) ^ fd);
            unsigned pk = *reinterpret_cast<const unsigned*>(
                (const char*)nvL + slot * 16 + (d2 & 3) * 4);
            float al = alphw[wv * 16 + s2];
            a0 += al * bf2f((u16)(pk & 0xffff));
            a1 += al * bf2f((u16)(pk >> 16));
        }
        unsigned pk2 = ((unsigned)f2bf(a1) << 16) | f2bf(a0);
        int slot2 = (4 + (d2 >> 4)) * 64 + cg2 * 16 + wv;
        *reinterpret_cast<unsigned*>((char*)A2 + slot2 * 16 + (d2 & 3) * 4) = pk2;
    }
    __syncthreads();

    // ---- GEMM2: out[16,128] = A2[16,256] @ W3T; wave owns 16 cols ----
    {
        f32x4 acc2 = (f32x4){0.f, 0.f, 0.f, 0.f};
        #pragma unroll
        for (int kk2 = 0; kk2 < 8; ++kk2) {
            short8v a2 = *reinterpret_cast<const short8v*>(A2 + (kk2 * 64 + lane) * 8);
            short8v bb = *reinterpret_cast<const short8v*>(w3th + nc * 256 + kk2 * 32 + cg * 8);
            acc2 = __builtin_amdgcn_mfma_f32_16x16x32_bf16(a2, bb, acc2, 0, 0, 0);
        }
        if (cg < 2) {                          // C rows 0..7 = l, 8..15 pad
            #pragma unroll
            for (int r = 0; r < 4; ++r) {
                int lg = l0 + cg * 4 + r;
                float v = fmaxf(acc2[r], 0.f);
                if (lg < L) {
                    if (PATH == 2) { float* p = outf + ((size_t)b * 50 + lg) * 128 + nc; *p += v; }
                    else           outb[((size_t)b * L + lg) * 128 + nc] = f2bf(v);
                }
            }
        }
    }
}

// ---------------------------------------------------------------------------
extern "C" void kernel_launch(void* const* d_in, const int* in_sizes, int n_in,
                              void* d_out, int out_size, void* d_ws, size_t ws_size,
                              hipStream_t stream)
{
    const int*   inputs     = (const int*)d_in[0];
    const int*   adj        = (const int*)d_in[1];
    const int*   mask_item  = (const int*)d_in[2];
    const int*   item       = (const int*)d_in[3];
    const int*   adj_all    = (const int*)d_in[4];
    const float* num_weight = (const float*)d_in[5];
    const float* embedding  = (const float*)d_in[6];
    const float* a_local    = (const float*)d_in[7];
    const float* agg_w1     = (const float*)d_in[8];
    const float* agg_w2     = (const float*)d_in[9];
    const float* agg_w3     = (const float*)d_in[10];
    float* out = (float*)d_out;

    // workspace layout (16B aligned)
    char* w = (char*)d_ws;
    float* ws_session = (float*)(w);               //     65,536 B
    int*   ws_n1      = (int*)(w + 65536);         //    307,200 B
    float* ws_nw0     = (float*)(w + 372736);      //    307,200 B
    float* ws_nw1     = (float*)(w + 679936);      //  3,686,400 B
    int*   ws_n2p     = (int*)(w + 4366336);       //  3,686,400 B
    int*   ws_n1p     = (int*)(w + 8052736);       //    344,064 B
    u16*   ws_emb     = (u16*)(w + 8396800);       // 10,240,000 B
    u16*   ws_sw1     = (u16*)(w + 18636800);      //  8,388,608 B
    u16*   ws_w3t     = (u16*)(w + 27025408);      //    131,072 B
    u16*   ws_out0    = (u16*)(w + 27156480);      //  1,638,400 B
    u16*   ws_out1    = (u16*)(w + 28794880);      // 19,660,800 B (end ~46.2 MB)

    setup1_kernel<<<dim3(BATCH + 300), 256, 0, stream>>>(
        item, mask_item, inputs, adj_all, num_weight, embedding,
        ws_session, ws_n1, ws_nw0);
    prep2_kernel<<<dim3(6724), 256, 0, stream>>>(
        embedding, agg_w1, agg_w3, ws_session, adj_all, num_weight, ws_n1,
        ws_emb, ws_sw1, ws_w3t, ws_n2p, ws_n1p, ws_nw1);

    // fused: local (bx=0) + mode0 (bx 1..7) + mode1 (bx 8..82) per batch
    main_kernel<0><<<dim3(83, BATCH), 512, 0, stream>>>(
        inputs, adj, ws_emb, a_local, ws_n1, ws_n2p, ws_n1p, ws_nw0, ws_nw1,
        ws_sw1, agg_w1, agg_w2, ws_w3t,
        nullptr, nullptr, ws_out0, ws_out1, out);

    // mode2: hop-1 weights, self=out0, neigh=out1, += h_local in d_out
    main_kernel<2><<<dim3(7, BATCH), 512, 0, stream>>>(
        inputs, adj, ws_emb, a_local, ws_n1, ws_n2p, ws_n1p, ws_nw0, ws_nw1,
        ws_sw1, agg_w1, agg_w2, ws_w3t,
        ws_out0, ws_out1, nullptr, nullptr, out);
}